// Round 1
// 44.563 us; speedup vs baseline: 1.0178x; 1.0178x over previous
//
#include <hip/hip_runtime.h>
#include <stdint.h>

#define B_N 16
#define C_N 64
#define O_N 64
#define H_N 128
#define W_N 128

typedef short bf16x8 __attribute__((ext_vector_type(8)));
typedef float f32x4 __attribute__((ext_vector_type(4)));
typedef unsigned short u16;
typedef u16 u16x4 __attribute__((ext_vector_type(4)));

__device__ __forceinline__ u16 f2bf(float f) {
    uint32_t u = __float_as_uint(f);
    u += 0x7FFFu + ((u >> 16) & 1u);
    return (u16)(u >> 16);
}

// Period-8 swizzle: permutation on EVERY 8-consecutive-w window (incl. the
// jsh=+-1 shifted read windows) -> b128 reads conflict-free. Write side pays
// ~8-way on b64 — now hidden under the MFMA phase by the restage pipeline.
__device__ __forceinline__ int swz(int w) { return (w & 7) << 4; }

// Pre-gather weights into exact B-fragment order:
// wf[b][ij][cs][of][lane][j8]  (bf16), total 16*9*2*4*64*8 = 589824 elems
// value = weight[b][(c)*9 + ij][o],  c = cs*32 + (lane>>4)*8 + j8,  o = of*16 + (lane&15)
__global__ __launch_bounds__(256) void prep_weights(const float* __restrict__ wt,
                                                    u16* __restrict__ wf) {
    int idx = blockIdx.x * 256 + threadIdx.x;
    int e = idx;
    int j8 = e & 7;  e >>= 3;
    int l  = e & 63; e >>= 6;
    int of = e & 3;  e >>= 2;
    int cs = e & 1;  e >>= 1;
    int ij = e % 9;
    int b  = e / 9;
    int c = cs * 32 + (l >> 4) * 8 + j8;
    int o = of * 16 + (l & 15);
    float v = wt[((size_t)b * 576 + (size_t)c * 9 + ij) * 64 + o];
    wf[idx] = f2bf(v);
}

// Main kernel v2: one workgroup per (b, 4-row h strip). Grid = 512 = exactly
// 2 blocks/CU resident, one dispatch round.
//  - Weights STREAMED via 3-deep rotating reg buffer (2-step prefetch) instead
//    of a 144-reg preload that spilled under the (256,2) cap.
//  - Circular 4-slot LDS row buffer; row r+3 is restaged (loads at ij==0/1,
//    convert+ds_write at ij==5/7) while row r computes -> staging hides under MFMA.
__global__ __launch_bounds__(256, 2) void conv_main(const float* __restrict__ x,
                                                    const u16* __restrict__ wf,
                                                    const float* __restrict__ bias,
                                                    float* __restrict__ y) {
    __shared__ u16 xl[4 * 128 * 64];   // 4 row-slots x [w][c] bf16, 64KB, swizzled

    // XCD-bijective swizzle: 512 wgs, 8 XCDs, chunk=64 -> XCD j owns 2 full b's.
    const int lid = (blockIdx.x & 7) * 64 + (blockIdx.x >> 3);
    const int b = lid >> 5;
    const int h0 = (lid & 31) * 4;
    const int tid = threadIdx.x;

    const int wid = tid >> 6;
    const int l = tid & 63;
    const int wave_m = wid >> 1;              // 0..1 -> pixel range
    const int wave_n = wid & 1;               // 0..1 -> o range
    const int m0 = wave_m * 64;
    const int o0 = wave_n * 32;
    const int lr = l & 15;
    const int lg = l >> 4;                    // k-group (0..3)

    const u16* wfb = wf + (size_t)b * (9 * 2 * 4 * 64 * 8);

    // Rotating weight-fragment buffer: step t uses wbuf[t%3]; loadw(t+2) at
    // iteration t rewrites the buffer consumed at t-1 (WAR throttles hoisting).
    bf16x8 wbuf[3][4];                         // [buf][cs*2+nf]
    auto loadw = [&](int t) {
        const int ij = t % 9;
        const u16* p = wfb + (size_t)(ij * 8 + wave_n * 2) * 512 + l * 8;
        bf16x8* d = wbuf[t % 3];
        d[0] = *reinterpret_cast<const bf16x8*>(p);          // cs0 nf0
        d[1] = *reinterpret_cast<const bf16x8*>(p + 512);    // cs0 nf1
        d[2] = *reinterpret_cast<const bf16x8*>(p + 2048);   // cs1 nf0
        d[3] = *reinterpret_cast<const bf16x8*>(p + 2560);   // cs1 nf1
    };

    loadw(0);
    loadw(1);

    float bv0 = bias[b * 64 + o0 + lr];
    float bv1 = bias[b * 64 + o0 + 16 + lr];

    // ---- Prologue: stage rows s=0..2 (input rows h0-1..h0+1) ----
#pragma unroll
    for (int it = 0; it < 6; ++it) {
        int task = it * 256 + tid;            // < 1536
        int w4 = task & 31;
        int cq = (task >> 5) & 15;
        int s  = task >> 9;                   // 0..2
        int hr = (h0 + s + 127) & 127;        // h0 + s - 1 mod 128
        const float* src = x + (((size_t)b * 64 + cq * 4) * 128 + hr) * 128 + w4 * 4;
        f32x4 L0 = *reinterpret_cast<const f32x4*>(src);
        f32x4 L1 = *reinterpret_cast<const f32x4*>(src + 16384);
        f32x4 L2 = *reinterpret_cast<const f32x4*>(src + 32768);
        f32x4 L3 = *reinterpret_cast<const f32x4*>(src + 49152);
#pragma unroll
        for (int j = 0; j < 4; ++j) {
            int w = w4 * 4 + j;
            u16x4 pk;
            pk.x = f2bf(L0[j]); pk.y = f2bf(L1[j]);
            pk.z = f2bf(L2[j]); pk.w = f2bf(L3[j]);
            int byte = s * 16384 + w * 128 + cq * 8;
            byte ^= swz(w);
            *reinterpret_cast<u16x4*>(reinterpret_cast<char*>(xl) + byte) = pk;
        }
    }
    __syncthreads();

    // ---- 4 output rows, software-pipelined ----
#pragma unroll
    for (int r = 0; r < 4; ++r) {
        f32x4 acc[4][2];
#pragma unroll
        for (int mf = 0; mf < 4; ++mf)
#pragma unroll
            for (int nf = 0; nf < 2; ++nf)
                acc[mf][nf] = (f32x4){0.f, 0.f, 0.f, 0.f};

        f32x4 st[8];                          // in-flight restage registers

#pragma unroll
        for (int ij = 0; ij < 9; ++ij) {
            const int t = r * 9 + ij;
            if (t + 2 < 36) loadw(t + 2);     // weight prefetch, 2-step lookahead

            // Restage row s=r+3 into slot (r+3)&3 (free during row r; all waves
            // are inside row r thanks to the per-row barrier).
            if (r < 3) {
                const int s = r + 3;
                if (ij == 0 || ij == 1) {
                    int task = ij * 256 + tid;
                    int w4 = task & 31, cq = task >> 5;
                    int hr = (h0 + s + 127) & 127;
                    const float* src = x + (((size_t)b * 64 + cq * 4) * 128 + hr) * 128 + w4 * 4;
                    f32x4* d = st + ij * 4;
                    d[0] = *reinterpret_cast<const f32x4*>(src);
                    d[1] = *reinterpret_cast<const f32x4*>(src + 16384);
                    d[2] = *reinterpret_cast<const f32x4*>(src + 32768);
                    d[3] = *reinterpret_cast<const f32x4*>(src + 49152);
                }
                if (ij == 5 || ij == 7) {
                    const int half = (ij == 5) ? 0 : 1;
                    int task = half * 256 + tid;
                    int w4 = task & 31, cq = task >> 5;
                    const f32x4* d = st + half * 4;
#pragma unroll
                    for (int j = 0; j < 4; ++j) {
                        int w = w4 * 4 + j;
                        u16x4 pk;
                        pk.x = f2bf(d[0][j]); pk.y = f2bf(d[1][j]);
                        pk.z = f2bf(d[2][j]); pk.w = f2bf(d[3][j]);
                        int byte = (s & 3) * 16384 + w * 128 + cq * 8;
                        byte ^= swz(w);
                        *reinterpret_cast<u16x4*>(reinterpret_cast<char*>(xl) + byte) = pk;
                    }
                }
            }

            const int i = ij / 3;             // staged row offset
            const int jsh = ij % 3 - 1;       // w shift
            const int rbase = ((r + i) & 3) * 16384;
#pragma unroll
            for (int cs = 0; cs < 2; ++cs) {
                bf16x8 afr[4];
                const int cb = cs * 64 + lg * 16;
#pragma unroll
                for (int mf = 0; mf < 4; ++mf) {
                    int w = (m0 + mf * 16 + lr + jsh + 128) & 127;
                    int byte = rbase + w * 128 + cb;
                    byte ^= swz(w);
                    afr[mf] = *reinterpret_cast<const bf16x8*>(
                        reinterpret_cast<const char*>(xl) + byte);
                }
                const bf16x8* wv = wbuf[t % 3];
#pragma unroll
                for (int mf = 0; mf < 4; ++mf) {
                    acc[mf][0] = __builtin_amdgcn_mfma_f32_16x16x32_bf16(afr[mf], wv[cs * 2 + 0], acc[mf][0], 0, 0, 0);
                    acc[mf][1] = __builtin_amdgcn_mfma_f32_16x16x32_bf16(afr[mf], wv[cs * 2 + 1], acc[mf][1], 0, 0, 0);
                }
            }
        }

        // ---- Epilogue: D layout col=lane&15 (o), row=(lane>>4)*4+reg (w) ----
        const int h = h0 + r;
#pragma unroll
        for (int nf = 0; nf < 2; ++nf) {
            int o = o0 + nf * 16 + lr;
            float bv = nf ? bv1 : bv0;
#pragma unroll
            for (int mf = 0; mf < 4; ++mf) {
                int w0 = m0 + mf * 16 + lg * 4;
                float* dst = y + (((size_t)b * 64 + o) * 128 + h) * 128 + w0;
                f32x4 out;
                out[0] = acc[mf][nf][0] + bv;
                out[1] = acc[mf][nf][1] + bv;
                out[2] = acc[mf][nf][2] + bv;
                out[3] = acc[mf][nf][3] + bv;
                *reinterpret_cast<f32x4*>(dst) = out;
            }
        }
        if (r < 3) __syncthreads();
    }
}

// Correctness-insurance fallback if workspace is too small (should not trigger).
__global__ void naive_conv(const float* __restrict__ x, const float* __restrict__ wt,
                           const float* __restrict__ bias, float* __restrict__ y) {
    int w = threadIdx.x;
    int h = blockIdx.x & 127;
    int o = (blockIdx.x >> 7) & 63;
    int b = blockIdx.x >> 13;
    float s = bias[b * 64 + o];
    for (int c = 0; c < 64; ++c)
        for (int i = 0; i < 3; ++i)
            for (int j = 0; j < 3; ++j) {
                int hh = (h + i + 127) & 127;
                int ww = (w + j + 127) & 127;
                s += x[(((size_t)b * 64 + c) * 128 + hh) * 128 + ww] *
                     wt[((size_t)b * 576 + (size_t)(c * 9 + i * 3 + j)) * 64 + o];
            }
    y[(((size_t)b * 64 + o) * 128 + h) * 128 + w] = s;
}

extern "C" void kernel_launch(void* const* d_in, const int* in_sizes, int n_in,
                              void* d_out, int out_size, void* d_ws, size_t ws_size,
                              hipStream_t stream) {
    const float* x    = (const float*)d_in[0];
    const float* wt   = (const float*)d_in[1];
    const float* bias = (const float*)d_in[2];
    float* y = (float*)d_out;

    const size_t WF_ELEMS = (size_t)B_N * 9 * 2 * 4 * 64 * 8;   // 589824
    const size_t WF_BYTES = WF_ELEMS * sizeof(u16);             // 1.18 MB

    if (ws_size >= WF_BYTES) {
        u16* wf = (u16*)d_ws;
        hipLaunchKernelGGL(prep_weights, dim3((unsigned)(WF_ELEMS / 256)), dim3(256), 0, stream, wt, wf);
        hipLaunchKernelGGL(conv_main, dim3(B_N * H_N / 4), dim3(256), 0, stream, x, wf, bias, y);
    } else {
        hipLaunchKernelGGL(naive_conv, dim3(B_N * O_N * H_N), dim3(128), 0, stream, x, wt, bias, y);
    }
}